// Round 2
// baseline (302.858 us; speedup 1.0000x reference)
//
#include <hip/hip_runtime.h>

// Fused SIREN-deform (3->32->32->32->3, cos) + trilinear sample from 256^3 vol.
// One thread per point; weights read via wave-uniform-address global loads
// (scalarize to s_load / same-address L1 hits); h[32]/g[32] in registers.
//
// NPTS is hardcoded: problem size is fixed (B=64, P=32 -> 2,097,152 points).
// Round-1 post-mortem: in_sizes[] appears to be in BYTES (dur was exactly 4x
// the VALU-floor prediction); npts = in_sizes[0]/4 = 4x too big caused a 24 MB
// out-of-bounds write that corrupted the harness's pristine input copies
// (first check passed, every post-restore launch failed identically).

#define NPTS (64 * 32 * 32 * 32)

__global__ __launch_bounds__(256)
void deform_sample(const float4* __restrict__ x,    // (N,4): cx,cy,cz,inten
                   const float4* __restrict__ W1,   // 3x32  = 24 float4
                   const float4* __restrict__ b1,   // 32    = 8 float4
                   const float4* __restrict__ W2,   // 32x32 = 256 float4
                   const float4* __restrict__ b2,
                   const float4* __restrict__ W3,
                   const float4* __restrict__ b3,
                   const float*  __restrict__ Wf,   // 32x3
                   const float*  __restrict__ bf,   // 3
                   const float*  __restrict__ vol,  // 256^3
                   float* __restrict__ out)
{
    int p = blockIdx.x * 256 + threadIdx.x;
    if (p >= NPTS) return;

    float4 xv = x[p];
    float c0 = xv.x, c1 = xv.y, c2 = xv.z;

    float h[32], g[32];

    // ---- layer 1: h = cos(c @ W1 + b1), W1[c][d] row-major ----
    #pragma unroll
    for (int j4 = 0; j4 < 8; ++j4) {
        float4 wa = W1[j4], wb = W1[8 + j4], wc = W1[16 + j4], bb = b1[j4];
        h[4*j4+0] = __cosf(fmaf(c0, wa.x, fmaf(c1, wb.x, fmaf(c2, wc.x, bb.x))));
        h[4*j4+1] = __cosf(fmaf(c0, wa.y, fmaf(c1, wb.y, fmaf(c2, wc.y, bb.y))));
        h[4*j4+2] = __cosf(fmaf(c0, wa.z, fmaf(c1, wb.z, fmaf(c2, wc.z, bb.z))));
        h[4*j4+3] = __cosf(fmaf(c0, wa.w, fmaf(c1, wb.w, fmaf(c2, wc.w, bb.w))));
    }

    // ---- layer 2: g = cos(h @ W2 + b2) ----
    #pragma unroll
    for (int j4 = 0; j4 < 8; ++j4) {
        float4 bb = b2[j4];
        g[4*j4+0] = bb.x; g[4*j4+1] = bb.y; g[4*j4+2] = bb.z; g[4*j4+3] = bb.w;
    }
    #pragma unroll
    for (int i = 0; i < 32; ++i) {
        float hv = h[i];
        #pragma unroll
        for (int j4 = 0; j4 < 8; ++j4) {
            float4 w = W2[i*8 + j4];
            g[4*j4+0] = fmaf(hv, w.x, g[4*j4+0]);
            g[4*j4+1] = fmaf(hv, w.y, g[4*j4+1]);
            g[4*j4+2] = fmaf(hv, w.z, g[4*j4+2]);
            g[4*j4+3] = fmaf(hv, w.w, g[4*j4+3]);
        }
    }
    #pragma unroll
    for (int j = 0; j < 32; ++j) g[j] = __cosf(g[j]);

    // ---- layer 3: h = cos(g @ W3 + b3) ----
    #pragma unroll
    for (int j4 = 0; j4 < 8; ++j4) {
        float4 bb = b3[j4];
        h[4*j4+0] = bb.x; h[4*j4+1] = bb.y; h[4*j4+2] = bb.z; h[4*j4+3] = bb.w;
    }
    #pragma unroll
    for (int i = 0; i < 32; ++i) {
        float gv = g[i];
        #pragma unroll
        for (int j4 = 0; j4 < 8; ++j4) {
            float4 w = W3[i*8 + j4];
            h[4*j4+0] = fmaf(gv, w.x, h[4*j4+0]);
            h[4*j4+1] = fmaf(gv, w.y, h[4*j4+1]);
            h[4*j4+2] = fmaf(gv, w.z, h[4*j4+2]);
            h[4*j4+3] = fmaf(gv, w.w, h[4*j4+3]);
        }
    }
    #pragma unroll
    for (int j = 0; j < 32; ++j) h[j] = __cosf(h[j]);

    // ---- final: c += 5 * (h @ Wf + bf), Wf[i][k] row-major ----
    float d0 = bf[0], d1 = bf[1], d2 = bf[2];
    #pragma unroll
    for (int i = 0; i < 32; ++i) {
        d0 = fmaf(h[i], Wf[3*i+0], d0);
        d1 = fmaf(h[i], Wf[3*i+1], d1);
        d2 = fmaf(h[i], Wf[3*i+2], d2);
    }
    c0 = fmaf(5.f, d0, c0);
    c1 = fmaf(5.f, d1, c1);
    c2 = fmaf(5.f, d2, c2);

    // ---- trilinear sample, vol (256,256,256,1), clip to [0,255] ----
    c0 = fminf(fmaxf(c0, 0.f), 255.f);
    c1 = fminf(fmaxf(c1, 0.f), 255.f);
    c2 = fminf(fmaxf(c2, 0.f), 255.f);
    float fl0 = floorf(c0), fl1 = floorf(c1), fl2 = floorf(c2);
    float fx = c0 - fl0, fy = c1 - fl1, fz = c2 - fl2;
    float gx = 1.f - fx, gy = 1.f - fy, gz = 1.f - fz;
    int x0 = (int)fl0, y0 = (int)fl1, z0 = (int)fl2;
    int x1 = min(x0 + 1, 255), y1 = min(y0 + 1, 255), z1 = min(z0 + 1, 255);
    int b00 = (x0 << 16) | (y0 << 8);
    int b01 = (x0 << 16) | (y1 << 8);
    int b10 = (x1 << 16) | (y0 << 8);
    int b11 = (x1 << 16) | (y1 << 8);
    float v000 = vol[b00 + z0], v001 = vol[b00 + z1];
    float v010 = vol[b01 + z0], v011 = vol[b01 + z1];
    float v100 = vol[b10 + z0], v101 = vol[b10 + z1];
    float v110 = vol[b11 + z0], v111 = vol[b11 + z1];

    float r = gz * (gy * (gx*v000 + fx*v100) + fy * (gx*v010 + fx*v110))
            + fz * (gy * (gx*v001 + fx*v101) + fy * (gx*v011 + fx*v111));

    out[p] = r;
}

extern "C" void kernel_launch(void* const* d_in, const int* in_sizes, int n_in,
                              void* d_out, int out_size, void* d_ws, size_t ws_size,
                              hipStream_t stream) {
    const float4* x   = (const float4*)d_in[0];
    const float4* W1  = (const float4*)d_in[1];
    const float4* b1  = (const float4*)d_in[2];
    const float4* W2  = (const float4*)d_in[3];
    const float4* b2  = (const float4*)d_in[4];
    const float4* W3  = (const float4*)d_in[5];
    const float4* b3  = (const float4*)d_in[6];
    const float*  Wf  = (const float*)d_in[7];
    const float*  bf  = (const float*)d_in[8];
    const float*  vol = (const float*)d_in[9];
    float* out = (float*)d_out;

    int grid = NPTS / 256;   // 8192 blocks, exact
    deform_sample<<<grid, 256, 0, stream>>>(x, W1, b1, W2, b2, W3, b3,
                                            Wf, bf, vol, out);
}

// Round 4
// 273.312 us; speedup vs baseline: 1.1081x; 1.1081x over previous
//
#include <hip/hip_runtime.h>

// Fused SIREN-deform (3->32->32->32->3, cos) + trilinear sample, MFMA version.
// Wave = 64 points. Layers 2/3 (32x32) via mfma_f32_16x16x32_bf16:
//   4 point-tiles x 2 feature-halves per layer. Activations live in a
//   wave-private LDS region (64 rows x 36 floats; stride 36 keeps float4 ops
//   16B-aligned and start-bank-uniform; scattered b32 writes are <=2-way).
// Round-4 change vs round-3: __threadfence_block() -> __syncthreads().
// Stage sync is intra-wave by construction, but a full barrier is ~100 cyc
// and closes any compiler-fence / non-atomic-reordering subtlety. In-place
// row overwrite inside a layer is ordered by dataflow (write consumes MFMA
// result which consumes the A-frag read of the same rows).
// Layouts (m89-verified): A[m=lane&15][k=(lane>>4)*8+j], B mirrored,
// C/D: col=lane&15 (feature), row=(lane>>4)*4+reg (point).

#define NPTS (64 * 32 * 32 * 32)
#define LSTR 36

typedef __attribute__((ext_vector_type(8))) short bf16x8;
typedef __attribute__((ext_vector_type(4))) float f32x4;

__device__ __forceinline__ short bf16rne(float f) {
    unsigned u = __builtin_bit_cast(unsigned, f);
    return (short)((u + 0x7fffu + ((u >> 16) & 1u)) >> 16);
}

__global__ __launch_bounds__(256)
void deform_sample_mfma(const float4* __restrict__ x,    // (N,4)
                        const float4* __restrict__ W1,   // 3x32
                        const float4* __restrict__ b1,   // 32
                        const float*  __restrict__ W2,   // 32x32 [k][n]
                        const float*  __restrict__ b2,
                        const float*  __restrict__ W3,
                        const float*  __restrict__ b3,
                        const float*  __restrict__ Wf,   // 32x3
                        const float*  __restrict__ bf,   // 3
                        const float*  __restrict__ vol,  // 256^3
                        float* __restrict__ out)
{
    __shared__ __align__(16) float lds[4 * 64 * LSTR];
    const int tid  = threadIdx.x;
    const int lane = tid & 63;
    const int wv   = tid >> 6;
    const int m16  = lane & 15;
    const int q    = lane >> 4;
    float* __restrict__ L = &lds[wv * 64 * LSTR];

    const int p = blockIdx.x * 256 + tid;   // own point (grid exact: 8192 blocks)

    // ---- B-fragments: W2/W3, feature halves, bf16. B[n=m16][k=q*8+j] ----
    bf16x8 Bf[4];
    {
        const float* Ws[2] = { W2, W3 };
        #pragma unroll
        for (int ly = 0; ly < 2; ++ly) {
            #pragma unroll
            for (int hf = 0; hf < 2; ++hf) {
                const float* W = Ws[ly];
                bf16x8 f;
                #pragma unroll
                for (int j = 0; j < 8; ++j)
                    f[j] = bf16rne(W[(q * 8 + j) * 32 + hf * 16 + m16]);
                Bf[2 * ly + hf] = f;
            }
        }
    }
    const float b2lo = b2[m16], b2hi = b2[m16 + 16];
    const float b3lo = b3[m16], b3hi = b3[m16 + 16];

    // ---- load own point; layer 1 per-lane: h = cos(c@W1 + b1) ----
    const float4 xv = x[p];
    const float c0 = xv.x, c1 = xv.y, c2 = xv.z;

    float h[32];
    #pragma unroll
    for (int j4 = 0; j4 < 8; ++j4) {
        float4 wa = W1[j4], wb = W1[8 + j4], wc = W1[16 + j4], bb = b1[j4];
        h[4*j4+0] = __cosf(fmaf(c0, wa.x, fmaf(c1, wb.x, fmaf(c2, wc.x, bb.x))));
        h[4*j4+1] = __cosf(fmaf(c0, wa.y, fmaf(c1, wb.y, fmaf(c2, wc.y, bb.y))));
        h[4*j4+2] = __cosf(fmaf(c0, wa.z, fmaf(c1, wb.z, fmaf(c2, wc.z, bb.z))));
        h[4*j4+3] = __cosf(fmaf(c0, wa.w, fmaf(c1, wb.w, fmaf(c2, wc.w, bb.w))));
    }

    // write h rows (row = lane), float4 x8
    {
        float4* row = (float4*)&L[lane * LSTR];
        #pragma unroll
        for (int j4 = 0; j4 < 8; ++j4)
            row[j4] = make_float4(h[4*j4+0], h[4*j4+1], h[4*j4+2], h[4*j4+3]);
    }
    __syncthreads();

    // ---- layers 2 and 3 via MFMA ----
    #pragma unroll
    for (int ly = 0; ly < 2; ++ly) {
        const float blo = ly ? b3lo : b2lo;
        const float bhi = ly ? b3hi : b2hi;
        #pragma unroll
        for (int t = 0; t < 4; ++t) {
            // A-frag: rows t*16+m16, k = q*8 + j
            const float4* ap = (const float4*)&L[(t * 16 + m16) * LSTR + q * 8];
            float4 a0 = ap[0], a1 = ap[1];
            bf16x8 af;
            af[0] = bf16rne(a0.x); af[1] = bf16rne(a0.y);
            af[2] = bf16rne(a0.z); af[3] = bf16rne(a0.w);
            af[4] = bf16rne(a1.x); af[5] = bf16rne(a1.y);
            af[6] = bf16rne(a1.z); af[7] = bf16rne(a1.w);

            f32x4 z = { 0.f, 0.f, 0.f, 0.f };
            f32x4 d0 = __builtin_amdgcn_mfma_f32_16x16x32_bf16(af, Bf[2*ly+0], z, 0, 0, 0);
            f32x4 d1 = __builtin_amdgcn_mfma_f32_16x16x32_bf16(af, Bf[2*ly+1], z, 0, 0, 0);

            // bias + cos, write back. row = t*16 + q*4 + r; feats m16, m16+16.
            // Ordered after this tile's A-frag reads by dataflow (d0/d1 <- af).
            #pragma unroll
            for (int r = 0; r < 4; ++r) {
                int prow = t * 16 + q * 4 + r;
                L[prow * LSTR + m16]      = __cosf(d0[r] + blo);
                L[prow * LSTR + m16 + 16] = __cosf(d1[r] + bhi);
            }
        }
        __syncthreads();
    }

    // ---- read back own row; final: c += 5*(h3@Wf + bf) ----
    float h3[32];
    {
        const float4* row = (const float4*)&L[lane * LSTR];
        #pragma unroll
        for (int j4 = 0; j4 < 8; ++j4) {
            float4 v = row[j4];
            h3[4*j4+0] = v.x; h3[4*j4+1] = v.y; h3[4*j4+2] = v.z; h3[4*j4+3] = v.w;
        }
    }

    float d0 = bf[0], d1 = bf[1], d2 = bf[2];
    #pragma unroll
    for (int i = 0; i < 32; ++i) {
        d0 = fmaf(h3[i], Wf[3*i+0], d0);
        d1 = fmaf(h3[i], Wf[3*i+1], d1);
        d2 = fmaf(h3[i], Wf[3*i+2], d2);
    }
    float e0 = fmaf(5.f, d0, c0);
    float e1 = fmaf(5.f, d1, c1);
    float e2 = fmaf(5.f, d2, c2);

    // ---- trilinear sample, vol (256,256,256,1) ----
    e0 = fminf(fmaxf(e0, 0.f), 255.f);
    e1 = fminf(fmaxf(e1, 0.f), 255.f);
    e2 = fminf(fmaxf(e2, 0.f), 255.f);
    float fl0 = floorf(e0), fl1 = floorf(e1), fl2 = floorf(e2);
    float fx = e0 - fl0, fy = e1 - fl1, fz = e2 - fl2;
    float gx = 1.f - fx, gy = 1.f - fy, gz = 1.f - fz;
    int x0 = (int)fl0, y0 = (int)fl1, z0 = (int)fl2;
    int x1 = min(x0 + 1, 255), y1 = min(y0 + 1, 255), z1 = min(z0 + 1, 255);
    int b00 = (x0 << 16) | (y0 << 8);
    int b01 = (x0 << 16) | (y1 << 8);
    int b10 = (x1 << 16) | (y0 << 8);
    int b11 = (x1 << 16) | (y1 << 8);
    float v000 = vol[b00 + z0], v001 = vol[b00 + z1];
    float v010 = vol[b01 + z0], v011 = vol[b01 + z1];
    float v100 = vol[b10 + z0], v101 = vol[b10 + z1];
    float v110 = vol[b11 + z0], v111 = vol[b11 + z1];

    float r = gz * (gy * (gx*v000 + fx*v100) + fy * (gx*v010 + fx*v110))
            + fz * (gy * (gx*v001 + fx*v101) + fy * (gx*v011 + fx*v111));

    out[p] = r;
}

extern "C" void kernel_launch(void* const* d_in, const int* in_sizes, int n_in,
                              void* d_out, int out_size, void* d_ws, size_t ws_size,
                              hipStream_t stream) {
    const float4* x   = (const float4*)d_in[0];
    const float4* W1  = (const float4*)d_in[1];
    const float4* b1  = (const float4*)d_in[2];
    const float*  W2  = (const float*)d_in[3];
    const float*  b2  = (const float*)d_in[4];
    const float*  W3  = (const float*)d_in[5];
    const float*  b3  = (const float*)d_in[6];
    const float*  Wf  = (const float*)d_in[7];
    const float*  bf  = (const float*)d_in[8];
    const float*  vol = (const float*)d_in[9];
    float* out = (float*)d_out;

    int grid = NPTS / 256;   // 8192 blocks, exact
    deform_sample_mfma<<<grid, 256, 0, stream>>>(x, W1, b1, W2, b2, W3, b3,
                                                 Wf, bf, vol, out);
}

// Round 5
// 267.746 us; speedup vs baseline: 1.1311x; 1.0208x over previous
//
#include <hip/hip_runtime.h>

// Fused SIREN-deform (3->32->32->32->3, cos) + trilinear sample, MFMA v2.
// Round-5 changes vs round-4 (which was latency-bound at 41% occupancy:
// VALU 31%, MFMA 2%, HBM 40% -- nothing saturated, LDS 36.9KB -> 4 blk/CU):
//  1. Activations in LDS as bf16, row stride 40 shorts (80 B): 20,480 B/block
//     -> 8 blocks/CU; __launch_bounds__(256,8) pins VGPR<=64.
//  2. MFMA operand roles swapped: A=weights (A[m=feat_out][k=feat_in], same
//     global gather expression as round-4's B-frag), B=activations (same LDS
//     read addresses as round-4's A-frag). D: col=point, row=feat_out quad --
//     each lane gets 4 CONSECUTIVE output feats of one point, so writeback is
//     2x ds_write_b64 per tile instead of 8 scattered b32.
// All stage sync via __syncthreads() (round-4-proven). In-tile read->write
// WAR is ordered by in-wave program order + dataflow (write consumes MFMA
// result which consumes the B-frag read).

#define NPTS (64 * 32 * 32 * 32)
#define SSTR 40   // shorts per LDS row: 80 B -> b128 rows 16B-aligned, <=2-way banks

typedef __attribute__((ext_vector_type(8))) short bf16x8;
typedef __attribute__((ext_vector_type(4))) short s16x4;
typedef __attribute__((ext_vector_type(4))) float f32x4;

__device__ __forceinline__ short bf16rne(float f) {
    unsigned u = __builtin_bit_cast(unsigned, f);
    return (short)((u + 0x7fffu + ((u >> 16) & 1u)) >> 16);
}
__device__ __forceinline__ float bf16tof(short s) {
    return __builtin_bit_cast(float, ((unsigned)(unsigned short)s) << 16);
}

__global__ __launch_bounds__(256, 8)
void deform_sample_mfma2(const float4* __restrict__ x,    // (N,4)
                         const float4* __restrict__ W1,   // 3x32
                         const float4* __restrict__ b1,   // 32
                         const float*  __restrict__ W2,   // 32x32 [in][out]
                         const float*  __restrict__ b2,
                         const float*  __restrict__ W3,
                         const float*  __restrict__ b3,
                         const float*  __restrict__ Wf,   // 32x3
                         const float*  __restrict__ bf_,  // 3
                         const float*  __restrict__ vol,  // 256^3
                         float* __restrict__ out)
{
    __shared__ short lds[4 * 64 * SSTR];   // 20,480 B
    const int tid  = threadIdx.x;
    const int lane = tid & 63;
    const int wv   = tid >> 6;
    const int m16  = lane & 15;
    const int q    = lane >> 4;
    short* __restrict__ L = &lds[wv * 64 * SSTR];

    const int p = blockIdx.x * 256 + tid;   // own point; grid exact 8192 blocks

    const float4 xv = x[p];
    const float c0 = xv.x, c1 = xv.y, c2 = xv.z;

    // ---- layer 1 per-lane: h = cos(c@W1+b1), bf16 rows into LDS (chunked) ----
    {
        bf16x8 hw;
        #pragma unroll
        for (int j4 = 0; j4 < 8; ++j4) {
            float4 wa = W1[j4], wb = W1[8 + j4], wc = W1[16 + j4], bb = b1[j4];
            float v0 = __cosf(fmaf(c0, wa.x, fmaf(c1, wb.x, fmaf(c2, wc.x, bb.x))));
            float v1 = __cosf(fmaf(c0, wa.y, fmaf(c1, wb.y, fmaf(c2, wc.y, bb.y))));
            float v2 = __cosf(fmaf(c0, wa.z, fmaf(c1, wb.z, fmaf(c2, wc.z, bb.z))));
            float v3 = __cosf(fmaf(c0, wa.w, fmaf(c1, wb.w, fmaf(c2, wc.w, bb.w))));
            int o = (j4 & 1) * 4;
            hw[o+0] = bf16rne(v0); hw[o+1] = bf16rne(v1);
            hw[o+2] = bf16rne(v2); hw[o+3] = bf16rne(v3);
            if (j4 & 1)   // write 8 feats: byte addr lane*80 + (j4-1)*8 -> 16B aligned
                *(bf16x8*)&L[lane * SSTR + (j4 - 1) * 4] = hw;
        }
    }
    __syncthreads();

    // ---- layers 2 and 3 via MFMA (A=weights, B=activations) ----
    const float* const Wly[2] = { W2, W3 };
    const float* const bly[2] = { b2, b3 };
    #pragma unroll
    for (int ly = 0; ly < 2; ++ly) {
        const float* __restrict__ W  = Wly[ly];
        const float* __restrict__ bb = bly[ly];
        // A-frags: A[m = m16 (+16 for hi half)][k = q*8+j] = W[k][m]
        bf16x8 A0, A1;
        #pragma unroll
        for (int j = 0; j < 8; ++j) {
            A0[j] = bf16rne(W[(q * 8 + j) * 32 + m16]);
            A1[j] = bf16rne(W[(q * 8 + j) * 32 + 16 + m16]);
        }
        // per-lane biases: lo half feats q*4+r, hi half 16+q*4+r (16B-aligned)
        const float4 blo = *(const float4*)&bb[q * 4];
        const float4 bhi = *(const float4*)&bb[16 + q * 4];

        #pragma unroll
        for (int t = 0; t < 4; ++t) {
            // B-frag: point row t*16+m16, feats q*8..q*8+7 (16B-aligned b128)
            bf16x8 bfrag = *(const bf16x8*)&L[(t * 16 + m16) * SSTR + q * 8];
            f32x4 z = { 0.f, 0.f, 0.f, 0.f };
            f32x4 d0 = __builtin_amdgcn_mfma_f32_16x16x32_bf16(A0, bfrag, z, 0, 0, 0);
            f32x4 d1 = __builtin_amdgcn_mfma_f32_16x16x32_bf16(A1, bfrag, z, 0, 0, 0);

            // D: col=point m16, row=feat q*4+r -> 4 consecutive feats/lane.
            s16x4 w0, w1;
            w0[0] = bf16rne(__cosf(d0[0] + blo.x));
            w0[1] = bf16rne(__cosf(d0[1] + blo.y));
            w0[2] = bf16rne(__cosf(d0[2] + blo.z));
            w0[3] = bf16rne(__cosf(d0[3] + blo.w));
            w1[0] = bf16rne(__cosf(d1[0] + bhi.x));
            w1[1] = bf16rne(__cosf(d1[1] + bhi.y));
            w1[2] = bf16rne(__cosf(d1[2] + bhi.z));
            w1[3] = bf16rne(__cosf(d1[3] + bhi.w));
            // two 8B writes: byte addr row*80 + q*8 (+32) -> 8B aligned
            *(s16x4*)&L[(t * 16 + m16) * SSTR + q * 4]      = w0;
            *(s16x4*)&L[(t * 16 + m16) * SSTR + 16 + q * 4] = w1;
        }
        __syncthreads();
    }

    // ---- read own row (bf16 -> f32 chunked); final c += 5*(h3@Wf + bf) ----
    float d0 = bf_[0], d1 = bf_[1], d2 = bf_[2];
    #pragma unroll
    for (int j4 = 0; j4 < 8; ++j4) {
        s16x4 v = *(const s16x4*)&L[lane * SSTR + j4 * 4];
        #pragma unroll
        for (int r = 0; r < 4; ++r) {
            float hv = bf16tof(v[r]);
            int i = j4 * 4 + r;
            d0 = fmaf(hv, Wf[3*i+0], d0);
            d1 = fmaf(hv, Wf[3*i+1], d1);
            d2 = fmaf(hv, Wf[3*i+2], d2);
        }
    }
    float e0 = fmaf(5.f, d0, c0);
    float e1 = fmaf(5.f, d1, c1);
    float e2 = fmaf(5.f, d2, c2);

    // ---- trilinear sample, vol (256,256,256,1) ----
    e0 = fminf(fmaxf(e0, 0.f), 255.f);
    e1 = fminf(fmaxf(e1, 0.f), 255.f);
    e2 = fminf(fmaxf(e2, 0.f), 255.f);
    float fl0 = floorf(e0), fl1 = floorf(e1), fl2 = floorf(e2);
    float fx = e0 - fl0, fy = e1 - fl1, fz = e2 - fl2;
    float gx = 1.f - fx, gy = 1.f - fy, gz = 1.f - fz;
    int x0 = (int)fl0, y0 = (int)fl1, z0 = (int)fl2;
    int x1 = min(x0 + 1, 255), y1 = min(y0 + 1, 255), z1 = min(z0 + 1, 255);
    int b00 = (x0 << 16) | (y0 << 8);
    int b01 = (x0 << 16) | (y1 << 8);
    int b10 = (x1 << 16) | (y0 << 8);
    int b11 = (x1 << 16) | (y1 << 8);
    float v000 = vol[b00 + z0], v001 = vol[b00 + z1];
    float v010 = vol[b01 + z0], v011 = vol[b01 + z1];
    float v100 = vol[b10 + z0], v101 = vol[b10 + z1];
    float v110 = vol[b11 + z0], v111 = vol[b11 + z1];

    float r = gz * (gy * (gx*v000 + fx*v100) + fy * (gx*v010 + fx*v110))
            + fz * (gy * (gx*v001 + fx*v101) + fy * (gx*v011 + fx*v111));

    out[p] = r;
}

extern "C" void kernel_launch(void* const* d_in, const int* in_sizes, int n_in,
                              void* d_out, int out_size, void* d_ws, size_t ws_size,
                              hipStream_t stream) {
    const float4* x   = (const float4*)d_in[0];
    const float4* W1  = (const float4*)d_in[1];
    const float4* b1  = (const float4*)d_in[2];
    const float*  W2  = (const float*)d_in[3];
    const float*  b2  = (const float*)d_in[4];
    const float*  W3  = (const float*)d_in[5];
    const float*  b3  = (const float*)d_in[6];
    const float*  Wf  = (const float*)d_in[7];
    const float*  bf_ = (const float*)d_in[8];
    const float*  vol = (const float*)d_in[9];
    float* out = (float*)d_out;

    int grid = NPTS / 256;   // 8192 blocks, exact
    deform_sample_mfma2<<<grid, 256, 0, stream>>>(x, W1, b1, W2, b2, W3, b3,
                                                  Wf, bf_, vol, out);
}